// Round 1
// baseline (653.277 us; speedup 1.0000x reference)
//
#include <hip/hip_runtime.h>

// ---------------------------------------------------------------------------
// RelationalNetwork: N=32, C=24, H=W=14, O=196, HD=128, GH=256, AS=28
// pairs[n,i,j] = [feats[n,j](26), feats[n,i](26), code[n](128)]  (D_IN=180)
// h1 = relu(pairs@gw0+gb0) = relu(AJ[n,j] + BI[n,i] + CC[n])   <- factorized
// h  = relu(h@gw{1,2,3}+gb{1,2,3})  (fused, bf16 MFMA, LDS-resident)
// relations[n] = sum over 196^2 pairs of h4
// logits = head MLP (fp32, tiny)
// ---------------------------------------------------------------------------

typedef __attribute__((ext_vector_type(8))) short short8;
typedef __attribute__((ext_vector_type(4))) float f32x4;

#define NIMG 32
#define O 196
#define GH 256
#define AS 28
#define ROWS 112           // pair-rows per block; 38416 = 112*343
#define CHUNKS 343
#define LDH 264            // padded LDS row stride (bf16 elems); 132 dwords

static __device__ __forceinline__ unsigned short f2bf(float f) {
    union { float f; unsigned int u; } v; v.f = f;
    unsigned int r = v.u + 0x7FFFu + ((v.u >> 16) & 1u);   // RNE
    return (unsigned short)(r >> 16);
}

// ---- setup kernel A: AJ[n,p,g], BI[n,p,g] (layer-0 factorization) ----------
__global__ void k_ajbi(const float* __restrict__ x, const float* __restrict__ gw0,
                       float* __restrict__ AJ, float* __restrict__ BI) {
    const int np = blockIdx.x;            // n*196 + p
    const int n = np / O, p = np - n * O;
    const int g = threadIdx.x;
    __shared__ float fs[26];
    if (g < 24)       fs[g]  = x[(n * 24 + g) * O + p];
    else if (g == 24) fs[24] = -7.0f + (float)(p / 14) * (14.0f / 13.0f);
    else if (g == 25) fs[25] = -7.0f + (float)(p % 14) * (14.0f / 13.0f);
    __syncthreads();
    float aj = 0.f, bi = 0.f;
#pragma unroll
    for (int c = 0; c < 26; ++c) {
        const float f = fs[c];
        aj = fmaf(f, gw0[c * GH + g], aj);
        bi = fmaf(f, gw0[(26 + c) * GH + g], bi);
    }
    AJ[np * GH + g] = aj;
    BI[np * GH + g] = bi;
}

// ---- setup kernel B: CC[n,g] = code[n] @ gw0[52:180] + gb0 -----------------
__global__ void k_cc(const float* __restrict__ code, const float* __restrict__ gw0,
                     const float* __restrict__ gb0, float* __restrict__ CC) {
    const int n = blockIdx.x, g = threadIdx.x;
    __shared__ float cs[128];
    if (g < 128) cs[g] = code[n * 128 + g];
    __syncthreads();
    float acc = gb0[g];
    for (int k = 0; k < 128; ++k) acc = fmaf(cs[k], gw0[(52 + k) * GH + g], acc);
    CC[n * GH + g] = acc;
}

// ---- setup kernel C: pack gw1/2/3 into bf16 MFMA B-fragment layout ---------
// packed[ ((ntile*8 + ks)*64 + lane)*8 + e ] = W[ ks*32 + (lane>>4)*8 + e ][ ntile*16 + (lane&15) ]
__global__ void k_pack(const float* __restrict__ gw1, const float* __restrict__ gw2,
                       const float* __restrict__ gw3, unsigned short* __restrict__ pW) {
    const int idx = blockIdx.x * 256 + threadIdx.x;     // 3*65536 total
    const int L = idx >> 16;
    const int rem = idx & 0xFFFF;
    const int e = rem & 7;
    const int lane = (rem >> 3) & 63;
    const int ks = (rem >> 9) & 7;
    const int ntile = rem >> 12;
    const int k = ks * 32 + ((lane >> 4) << 3) + e;
    const int col = ntile * 16 + (lane & 15);
    const float* W = (L == 0) ? gw1 : (L == 1) ? gw2 : gw3;
    pW[idx] = f2bf(W[k * GH + col]);
}

// ---- main fused kernel: h1 build + 3 GEMM layers + sum-pool ----------------
__global__ __launch_bounds__(256, 2) void k_main(
    const float* __restrict__ AJ, const float* __restrict__ BI,
    const float* __restrict__ CC, const unsigned short* __restrict__ pW,
    const float* __restrict__ gb1, const float* __restrict__ gb2,
    const float* __restrict__ gb3, float* __restrict__ rel) {
    __shared__ __attribute__((aligned(16))) unsigned short h[ROWS * LDH];

    const int blk = blockIdx.x;           // n*343 + chunk
    const int n = blk / CHUNKS;
    const int chunk = blk - n * CHUNKS;
    const int row_base = chunk * ROWS;
    const int t = threadIdx.x;
    const int wave = t >> 6;
    const int lane = t & 63;
    const int l15 = lane & 15;
    const int q = lane >> 4;

    // ---- phase 0: h1 = relu(AJ[j] + BI[i] + CC) -> LDS (bf16) ----
    {
        const float cc = CC[n * GH + t];
        int i = row_base / O;
        int j = row_base - i * O;
        const float* ajb = AJ + (n * O) * GH + t;
        const float* bib = BI + (n * O) * GH + t;
        for (int e = 0; e < ROWS; ++e) {
            float v = ajb[j * GH] + bib[i * GH] + cc;
            h[e * LDH + t] = f2bf(fmaxf(v, 0.0f));
            if (++j == O) { j = 0; ++i; }
        }
    }
    __syncthreads();

    const float* gbs[3] = {gb1, gb2, gb3};
    for (int layer = 0; layer < 3; ++layer) {
        f32x4 acc[7][4];
#pragma unroll
        for (int mt = 0; mt < 7; ++mt)
#pragma unroll
            for (int nt = 0; nt < 4; ++nt) acc[mt][nt] = (f32x4){0.f, 0.f, 0.f, 0.f};

        const short8* wp = (const short8*)(pW + layer * 65536);
        const int lds_base = l15 * LDH + q * 8;   // elems
#pragma unroll 2
        for (int ks = 0; ks < 8; ++ks) {
            short8 b[4];
#pragma unroll
            for (int nt = 0; nt < 4; ++nt)
                b[nt] = wp[((wave * 4 + nt) * 8 + ks) * 64 + lane];
            short8 a[7];
#pragma unroll
            for (int mt = 0; mt < 7; ++mt)
                a[mt] = *(const short8*)&h[mt * 16 * LDH + lds_base + ks * 32];
#pragma unroll
            for (int mt = 0; mt < 7; ++mt)
#pragma unroll
                for (int nt = 0; nt < 4; ++nt)
                    acc[mt][nt] = __builtin_amdgcn_mfma_f32_16x16x32_bf16(
                        a[mt], b[nt], acc[mt][nt], 0, 0, 0);
        }
        __syncthreads();

        const float* gb = gbs[layer];
        if (layer < 2) {
            // bias + relu -> bf16 back into LDS (each wave owns 64 cols)
#pragma unroll
            for (int nt = 0; nt < 4; ++nt) {
                const int col = wave * 64 + nt * 16 + l15;
                const float bias = gb[col];
#pragma unroll
                for (int mt = 0; mt < 7; ++mt) {
#pragma unroll
                    for (int r = 0; r < 4; ++r) {
                        const int row = mt * 16 + q * 4 + r;
                        h[row * LDH + col] = f2bf(fmaxf(acc[mt][nt][r] + bias, 0.0f));
                    }
                }
            }
            __syncthreads();
        } else {
            // final layer: bias + relu + column-sum over 112 rows -> atomicAdd
#pragma unroll
            for (int nt = 0; nt < 4; ++nt) {
                const int col = wave * 64 + nt * 16 + l15;
                const float bias = gb[col];
                float s = 0.f;
#pragma unroll
                for (int mt = 0; mt < 7; ++mt)
#pragma unroll
                    for (int r = 0; r < 4; ++r)
                        s += fmaxf(acc[mt][nt][r] + bias, 0.0f);
                s += __shfl_xor(s, 16);
                s += __shfl_xor(s, 32);
                if (q == 0) atomicAdd(&rel[n * GH + col], s);
            }
        }
    }
}

// ---- head MLP (fp32, tiny): relations -> logits ----------------------------
__global__ void k_fmlp(const float* __restrict__ rel,
                       const float* __restrict__ fw0, const float* __restrict__ fb0,
                       const float* __restrict__ fw1, const float* __restrict__ fb1,
                       const float* __restrict__ fw2, const float* __restrict__ fb2,
                       float* __restrict__ out) {
    __shared__ float b0[GH], b1[GH];
    const int n = blockIdx.x, g = threadIdx.x;
    b0[g] = rel[n * GH + g];
    __syncthreads();
    float a = fb0[g];
    for (int k = 0; k < GH; ++k) a = fmaf(b0[k], fw0[k * GH + g], a);
    b1[g] = fmaxf(a, 0.f);
    __syncthreads();
    float c = fb1[g];
    for (int k = 0; k < GH; ++k) c = fmaf(b1[k], fw1[k * GH + g], c);
    b0[g] = fmaxf(c, 0.f);
    __syncthreads();
    if (g < AS) {
        float o = fb2[g];
        for (int k = 0; k < GH; ++k) o = fmaf(b0[k], fw2[k * AS + g], o);
        out[n * AS + g] = o;
    }
}

// ---------------------------------------------------------------------------
extern "C" void kernel_launch(void* const* d_in, const int* in_sizes, int n_in,
                              void* d_out, int out_size, void* d_ws, size_t ws_size,
                              hipStream_t stream) {
    const float* x    = (const float*)d_in[0];
    const float* code = (const float*)d_in[1];
    const float* gw0  = (const float*)d_in[2];
    const float* gb0  = (const float*)d_in[3];
    const float* gw1  = (const float*)d_in[4];
    const float* gb1  = (const float*)d_in[5];
    const float* gw2  = (const float*)d_in[6];
    const float* gb2  = (const float*)d_in[7];
    const float* gw3  = (const float*)d_in[8];
    const float* gb3  = (const float*)d_in[9];
    const float* fw0  = (const float*)d_in[10];
    const float* fb0  = (const float*)d_in[11];
    const float* fw1  = (const float*)d_in[12];
    const float* fb1  = (const float*)d_in[13];
    const float* fw2  = (const float*)d_in[14];
    const float* fb2  = (const float*)d_in[15];
    float* out = (float*)d_out;

    char* ws = (char*)d_ws;
    // workspace layout (16B aligned)
    float*          AJ  = (float*)(ws + 0);                 // 32*196*256*4 = 6,422,528
    float*          BI  = (float*)(ws + 6422528);           // 6,422,528
    float*          CC  = (float*)(ws + 12845056);          // 32,768
    float*          rel = (float*)(ws + 12877824);          // 32,768
    unsigned short* pW  = (unsigned short*)(ws + 12910592); // 3*65536*2 = 393,216

    hipMemsetAsync(rel, 0, NIMG * GH * sizeof(float), stream);
    k_ajbi<<<NIMG * O, 256, 0, stream>>>(x, gw0, AJ, BI);
    k_cc<<<NIMG, 256, 0, stream>>>(code, gw0, gb0, CC);
    k_pack<<<3 * 256, 256, 0, stream>>>(gw1, gw2, gw3, pW);
    k_main<<<NIMG * CHUNKS, 256, 0, stream>>>(AJ, BI, CC, pW, gb1, gb2, gb3, rel);
    k_fmlp<<<NIMG, 256, 0, stream>>>(rel, fw0, fb0, fw1, fb1, fw2, fb2, out);
}

// Round 2
// 525.540 us; speedup vs baseline: 1.2431x; 1.2431x over previous
//
#include <hip/hip_runtime.h>
#include <hip/hip_bf16.h>

// ---------------------------------------------------------------------------
// RelationalNetwork: N=32, C=24, H=W=14, O=196, HD=128, GH=256, AS=28
// pairs[n,i,j] = [feats[n,j](26), feats[n,i](26), code[n](128)]  (D_IN=180)
// h1 = relu(AJ'[n,j] + BI[n,i])        AJ' has CC (code-term) + gb0 folded in
// h  = relu(h@gw{1,2,3}+gb)            fused, bf16 MFMA 16x16x32, LDS-resident
// relations[n] = sum over 196^2 pairs  -> head MLP (fp32, tiny)
//
// Round 2: ROWS 112->128 (tail-masked), 8 waves (2M x 4N), LDS = 64KiB exactly
// via XOR swizzle (byte ^ ((row&7)<<4)) -> 2 blocks/CU = 4 waves/SIMD (was 2).
// Phase-0 vectorized float4 + hoisted BI rows + native bf16 cvt.
// ---------------------------------------------------------------------------

typedef __attribute__((ext_vector_type(8))) short short8;
typedef __attribute__((ext_vector_type(4))) float f32x4;

#define NIMG 32
#define O 196
#define PAIRS 38416
#define GH 256
#define AS 28
#define ROWS 128
#define CHUNKS 301          // 300*128 + 16 = 38416 (tail chunk: 16 valid rows)

static __device__ __forceinline__ unsigned short f2bf(float f) {
    __hip_bfloat16 h = __float2bfloat16(f);
    return *reinterpret_cast<unsigned short*>(&h);
}

// ---- setup kernel B: CC[n,g] = code[n] @ gw0[52:180] + gb0 -----------------
__global__ void k_cc(const float* __restrict__ code, const float* __restrict__ gw0,
                     const float* __restrict__ gb0, float* __restrict__ CC) {
    const int n = blockIdx.x, g = threadIdx.x;
    __shared__ float cs[128];
    if (g < 128) cs[g] = code[n * 128 + g];
    __syncthreads();
    float acc = gb0[g];
    for (int k = 0; k < 128; ++k) acc = fmaf(cs[k], gw0[(52 + k) * GH + g], acc);
    CC[n * GH + g] = acc;
}

// ---- setup kernel A: AJ'[n,p,g] (includes CC), BI[n,p,g] -------------------
__global__ void k_ajbi(const float* __restrict__ x, const float* __restrict__ gw0,
                       const float* __restrict__ CC,
                       float* __restrict__ AJ, float* __restrict__ BI) {
    const int np = blockIdx.x;            // n*196 + p
    const int n = np / O, p = np - n * O;
    const int g = threadIdx.x;
    __shared__ float fs[26];
    if (g < 24)       fs[g]  = x[(n * 24 + g) * O + p];
    else if (g == 24) fs[24] = -7.0f + (float)(p / 14) * (14.0f / 13.0f);
    else if (g == 25) fs[25] = -7.0f + (float)(p % 14) * (14.0f / 13.0f);
    __syncthreads();
    float aj = CC[n * GH + g], bi = 0.f;
#pragma unroll
    for (int c = 0; c < 26; ++c) {
        const float f = fs[c];
        aj = fmaf(f, gw0[c * GH + g], aj);
        bi = fmaf(f, gw0[(26 + c) * GH + g], bi);
    }
    AJ[np * GH + g] = aj;
    BI[np * GH + g] = bi;
}

// ---- setup kernel C: pack gw1/2/3 into bf16 MFMA B-fragment layout ---------
// packed[((ntile*8+ks)*64+lane)*8+e] = W[ks*32+(lane>>4)*8+e][ntile*16+(lane&15)]
__global__ void k_pack(const float* __restrict__ gw1, const float* __restrict__ gw2,
                       const float* __restrict__ gw3, unsigned short* __restrict__ pW) {
    const int idx = blockIdx.x * 256 + threadIdx.x;     // 3*65536 total
    const int L = idx >> 16;
    const int rem = idx & 0xFFFF;
    const int e = rem & 7;
    const int lane = (rem >> 3) & 63;
    const int ks = (rem >> 9) & 7;
    const int ntile = rem >> 12;
    const int k = ks * 32 + ((lane >> 4) << 3) + e;
    const int col = ntile * 16 + (lane & 15);
    const float* W = (L == 0) ? gw1 : (L == 1) ? gw2 : gw3;
    pW[idx] = f2bf(W[k * GH + col]);
}

// ---- main fused kernel: h1 build + 3 GEMM layers + sum-pool ----------------
__global__ __launch_bounds__(512, 4) void k_main(
    const float* __restrict__ AJ, const float* __restrict__ BI,
    const unsigned short* __restrict__ pW,
    const float* __restrict__ gb1, const float* __restrict__ gb2,
    const float* __restrict__ gb3, float* __restrict__ rel) {
    // 128 rows x 256 cols bf16, XOR-swizzled: byte ^= ((row&7)<<4). 64 KiB.
    __shared__ __attribute__((aligned(16))) unsigned short h[ROWS * GH];

    const int blk = blockIdx.x;           // n*301 + chunk
    const int n = blk / CHUNKS;
    const int chunk = blk - n * CHUNKS;
    const int row_base = chunk * ROWS;
    const int t = threadIdx.x;
    const int wave = t >> 6;              // 0..7
    const int lane = t & 63;
    const int l15 = lane & 15;
    const int q = lane >> 4;
    const int mh = wave >> 2;             // M half  (rows mh*64 .. +63)
    const int wq = wave & 3;              // N quarter (cols wq*64 .. +63)
    const bool tail = (chunk == CHUNKS - 1);

    // ---- phase 0: h1 = relu(AJ'[j] + BI[i]) -> LDS (bf16, swizzled) ----
    // Each wave: 16 rows (r = wave + 8e), 64 lanes x 4 cols = full 256-col row.
    // i spans at most {i0, i0+1} within a 128-row chunk; BI rows hoisted.
    {
        const int i0 = row_base / O;
        const int j00 = row_base - i0 * O;
        const int i1 = min(i0 + 1, O - 1);
        const float4 bi0 = *(const float4*)&BI[(n * O + i0) * GH + lane * 4];
        const float4 bi1 = *(const float4*)&BI[(n * O + i1) * GH + lane * 4];
        for (int e = 0; e < 16; ++e) {
            const int r = wave + e * 8;
            const int jj = j00 + r;                 // <= 195+127, one wrap max
            const bool wrap = (jj >= O);
            const int j = wrap ? jj - O : jj;       // tail garbage rows read
            const float4 aj = *(const float4*)&AJ[(n * O + j) * GH + lane * 4];
            const float4 bi = wrap ? bi1 : bi0;     // in-range rows; masked later
            const unsigned int lo = (unsigned)f2bf(fmaxf(aj.x + bi.x, 0.f)) |
                                    ((unsigned)f2bf(fmaxf(aj.y + bi.y, 0.f)) << 16);
            const unsigned int hi = (unsigned)f2bf(fmaxf(aj.z + bi.z, 0.f)) |
                                    ((unsigned)f2bf(fmaxf(aj.w + bi.w, 0.f)) << 16);
            const int byteoff = r * 512 + ((lane * 8) ^ ((r & 7) << 4));
            uint2 dd; dd.x = lo; dd.y = hi;
            *(uint2*)((char*)h + byteoff) = dd;
        }
    }
    __syncthreads();

    const float* gbs[3] = {gb1, gb2, gb3};
    const int X = (l15 & 7) << 4;                       // A-read swizzle (lane-const)
    const char* hb = (const char*)h + (mh * 64 + l15) * 512;
    const int cb2 = (wq * 64 + l15) * 2;                // epilogue col byte base

    for (int layer = 0; layer < 3; ++layer) {
        f32x4 acc[4][4];
#pragma unroll
        for (int mt = 0; mt < 4; ++mt)
#pragma unroll
            for (int nt = 0; nt < 4; ++nt) acc[mt][nt] = (f32x4){0.f, 0.f, 0.f, 0.f};

        const short8* wp = (const short8*)(pW + layer * 65536);
#pragma unroll 1
        for (int ks = 0; ks < 8; ++ks) {
            short8 b[4];
#pragma unroll
            for (int nt = 0; nt < 4; ++nt)
                b[nt] = wp[((wq * 4 + nt) * 8 + ks) * 64 + lane];
            const int off = (ks * 64 + q * 16) ^ X;     // swizzled k-offset
            short8 a[4];
#pragma unroll
            for (int mt = 0; mt < 4; ++mt)
                a[mt] = *(const short8*)(hb + off + mt * 8192);
#pragma unroll
            for (int mt = 0; mt < 4; ++mt)
#pragma unroll
                for (int nt = 0; nt < 4; ++nt)
                    acc[mt][nt] = __builtin_amdgcn_mfma_f32_16x16x32_bf16(
                        a[mt], b[nt], acc[mt][nt], 0, 0, 0);
        }
        __syncthreads();

        const float* gb = gbs[layer];
        if (layer < 2) {
            // bias + relu -> bf16 back to LDS (swizzled b16 stores)
#pragma unroll
            for (int nt = 0; nt < 4; ++nt) {
                const float bias = gb[wq * 64 + nt * 16 + l15];
#pragma unroll
                for (int r = 0; r < 4; ++r) {
                    const int rowl = q * 4 + r;
                    const int base = (((mh * 64 + rowl) * 512) + cb2 + nt * 32)
                                     ^ ((rowl & 7) << 4);
#pragma unroll
                    for (int mt = 0; mt < 4; ++mt)
                        *(unsigned short*)((char*)h + base + mt * 8192) =
                            f2bf(fmaxf(acc[mt][nt][r] + bias, 0.0f));
                }
            }
            __syncthreads();
        } else {
            // final: bias + relu + column-sum (tail chunk: only rows 0..15 valid
            // = mh==0 && mt==0; wave-uniform mask)
#pragma unroll
            for (int nt = 0; nt < 4; ++nt) {
                const int col = wq * 64 + nt * 16 + l15;
                const float bias = gb[col];
                float s = 0.f;
#pragma unroll
                for (int mt = 0; mt < 4; ++mt) {
                    if (tail && !(mh == 0 && mt == 0)) continue;
#pragma unroll
                    for (int r = 0; r < 4; ++r)
                        s += fmaxf(acc[mt][nt][r] + bias, 0.0f);
                }
                s += __shfl_xor(s, 16);
                s += __shfl_xor(s, 32);
                if (q == 0) atomicAdd(&rel[n * GH + col], s);
            }
        }
    }
}

// ---- head MLP (fp32, tiny): relations -> logits ----------------------------
__global__ void k_fmlp(const float* __restrict__ rel,
                       const float* __restrict__ fw0, const float* __restrict__ fb0,
                       const float* __restrict__ fw1, const float* __restrict__ fb1,
                       const float* __restrict__ fw2, const float* __restrict__ fb2,
                       float* __restrict__ out) {
    __shared__ float b0[GH], b1[GH];
    const int n = blockIdx.x, g = threadIdx.x;
    b0[g] = rel[n * GH + g];
    __syncthreads();
    float a = fb0[g];
    for (int k = 0; k < GH; ++k) a = fmaf(b0[k], fw0[k * GH + g], a);
    b1[g] = fmaxf(a, 0.f);
    __syncthreads();
    float c = fb1[g];
    for (int k = 0; k < GH; ++k) c = fmaf(b1[k], fw1[k * GH + g], c);
    b0[g] = fmaxf(c, 0.f);
    __syncthreads();
    if (g < AS) {
        float o = fb2[g];
        for (int k = 0; k < GH; ++k) o = fmaf(b0[k], fw2[k * AS + g], o);
        out[n * AS + g] = o;
    }
}

// ---------------------------------------------------------------------------
extern "C" void kernel_launch(void* const* d_in, const int* in_sizes, int n_in,
                              void* d_out, int out_size, void* d_ws, size_t ws_size,
                              hipStream_t stream) {
    const float* x    = (const float*)d_in[0];
    const float* code = (const float*)d_in[1];
    const float* gw0  = (const float*)d_in[2];
    const float* gb0  = (const float*)d_in[3];
    const float* gw1  = (const float*)d_in[4];
    const float* gb1  = (const float*)d_in[5];
    const float* gw2  = (const float*)d_in[6];
    const float* gb2  = (const float*)d_in[7];
    const float* gw3  = (const float*)d_in[8];
    const float* gb3  = (const float*)d_in[9];
    const float* fw0  = (const float*)d_in[10];
    const float* fb0  = (const float*)d_in[11];
    const float* fw1  = (const float*)d_in[12];
    const float* fb1  = (const float*)d_in[13];
    const float* fw2  = (const float*)d_in[14];
    const float* fb2  = (const float*)d_in[15];
    float* out = (float*)d_out;

    char* ws = (char*)d_ws;
    // workspace layout (16B aligned)
    float*          AJ  = (float*)(ws + 0);                 // 32*196*256*4 = 6,422,528
    float*          BI  = (float*)(ws + 6422528);           // 6,422,528
    float*          CC  = (float*)(ws + 12845056);          // 32,768
    float*          rel = (float*)(ws + 12877824);          // 32,768
    unsigned short* pW  = (unsigned short*)(ws + 12910592); // 3*65536*2 = 393,216

    hipMemsetAsync(rel, 0, NIMG * GH * sizeof(float), stream);
    k_cc<<<NIMG, 256, 0, stream>>>(code, gw0, gb0, CC);
    k_ajbi<<<NIMG * O, 256, 0, stream>>>(x, gw0, CC, AJ, BI);
    k_pack<<<3 * 256, 256, 0, stream>>>(gw1, gw2, gw3, pW);
    k_main<<<NIMG * CHUNKS, 512, 0, stream>>>(AJ, BI, pW, gb1, gb2, gb3, rel);
    k_fmlp<<<NIMG, 256, 0, stream>>>(rel, fw0, fb0, fw1, fb1, fw2, fb2, out);
}